// Round 1
// baseline (275.153 us; speedup 1.0000x reference)
//
#include <hip/hip_runtime.h>
#include <cfloat>
#include <math.h>

#define NCLS 1000
#define VEC (NCLS / 4)  // 250 float4 per row

// One block (256 threads = 4 waves) per row.
// Per row: m1=max(f1), m2=max(f2), S1=sum exp(f1-m1), S2=sum exp(f2-m2),
//          T = sum exp(f2-m2)*(f2-f1)
// row_kl = T/S2 - ((m2-m1) + log(S2) - log(S1))
__global__ __launch_bounds__(256) void rowkl_kernel(
    const float* __restrict__ f1, const float* __restrict__ f2,
    const int* __restrict__ label,
    float* __restrict__ seg, float* __restrict__ cnt) {
  __shared__ float lds[20];
  const int row = blockIdx.x;
  const int t = threadIdx.x;
  const float4* r1 = reinterpret_cast<const float4*>(f1 + (size_t)row * NCLS);
  const float4* r2 = reinterpret_cast<const float4*>(f2 + (size_t)row * NCLS);
  const bool valid = (t < VEC);

  float4 a = make_float4(0.f, 0.f, 0.f, 0.f);
  float4 b = make_float4(0.f, 0.f, 0.f, 0.f);
  if (valid) { a = r1[t]; b = r2[t]; }

  float m1 = valid ? fmaxf(fmaxf(a.x, a.y), fmaxf(a.z, a.w)) : -FLT_MAX;
  float m2 = valid ? fmaxf(fmaxf(b.x, b.y), fmaxf(b.z, b.w)) : -FLT_MAX;

  #pragma unroll
  for (int o = 32; o >= 1; o >>= 1) {
    m1 = fmaxf(m1, __shfl_xor(m1, o));
    m2 = fmaxf(m2, __shfl_xor(m2, o));
  }
  const int wid = t >> 6;
  if ((t & 63) == 0) { lds[wid] = m1; lds[4 + wid] = m2; }
  __syncthreads();
  m1 = fmaxf(fmaxf(lds[0], lds[1]), fmaxf(lds[2], lds[3]));
  m2 = fmaxf(fmaxf(lds[4], lds[5]), fmaxf(lds[6], lds[7]));

  float e1 = 0.f, e2 = 0.f, T = 0.f;
  if (valid) {
    e1 = __expf(a.x - m1) + __expf(a.y - m1) + __expf(a.z - m1) + __expf(a.w - m1);
    const float t0 = __expf(b.x - m2), t1 = __expf(b.y - m2);
    const float t2 = __expf(b.z - m2), t3 = __expf(b.w - m2);
    e2 = t0 + t1 + t2 + t3;
    T = t0 * (b.x - a.x) + t1 * (b.y - a.y) + t2 * (b.z - a.z) + t3 * (b.w - a.w);
  }
  #pragma unroll
  for (int o = 32; o >= 1; o >>= 1) {
    e1 += __shfl_xor(e1, o);
    e2 += __shfl_xor(e2, o);
    T  += __shfl_xor(T, o);
  }
  if ((t & 63) == 0) { lds[8 + wid] = e1; lds[12 + wid] = e2; lds[16 + wid] = T; }
  __syncthreads();
  if (t == 0) {
    e1 = lds[8]  + lds[9]  + lds[10] + lds[11];
    e2 = lds[12] + lds[13] + lds[14] + lds[15];
    T  = lds[16] + lds[17] + lds[18] + lds[19];
    const float rkl = T / e2 - ((m2 - m1) + __logf(e2) - __logf(e1));
    const int l = label[row];
    atomicAdd(&seg[l], rkl);
    atomicAdd(&cnt[l], 1.0f);
  }
}

__global__ __launch_bounds__(256) void finalize_kernel(
    const float* __restrict__ seg, const float* __restrict__ cnt,
    float* __restrict__ out) {
  __shared__ float lds[4];
  float s = 0.f;
  for (int c = threadIdx.x; c < NCLS; c += 256) {
    const float n = cnt[c];
    if (n > 0.f) s += seg[c] / (n * (float)NCLS);
  }
  #pragma unroll
  for (int o = 32; o >= 1; o >>= 1) s += __shfl_xor(s, o);
  const int wid = threadIdx.x >> 6;
  if ((threadIdx.x & 63) == 0) lds[wid] = s;
  __syncthreads();
  if (threadIdx.x == 0) out[0] = lds[0] + lds[1] + lds[2] + lds[3];
}

extern "C" void kernel_launch(void* const* d_in, const int* in_sizes, int n_in,
                              void* d_out, int out_size, void* d_ws, size_t ws_size,
                              hipStream_t stream) {
  const float* f1 = (const float*)d_in[0];
  const float* f2 = (const float*)d_in[1];
  const int* label = (const int*)d_in[2];
  float* seg = (float*)d_ws;
  float* cnt = seg + NCLS;

  hipMemsetAsync(d_ws, 0, 2 * NCLS * sizeof(float), stream);

  const int B = in_sizes[0] / NCLS;  // 32768
  rowkl_kernel<<<B, 256, 0, stream>>>(f1, f2, label, seg, cnt);
  finalize_kernel<<<1, 256, 0, stream>>>(seg, cnt, (float*)d_out);
}